// Round 1
// baseline (854.984 us; speedup 1.0000x reference)
//
#include <hip/hip_runtime.h>
#include <cstdint>
#include <cstddef>

#define D_MODEL 2048
#define EPSF 1e-5f

// workspace layout (float offsets)
#define WS_UT    0          // u/h transposed [4][8][4096] = 131072
#define WS_MU1   131072     // [16384]
#define WS_RSIG1 147456     // [16384]
#define WS_MU2   163840     // [16384]
#define WS_RSIG2 180224     // [16384]
#define WS_PRAW  196608     // [16384][32] = 524288
#define WS_WDT   720896     // gamma-folded W_down^T [32][2048] = 65536
#define WS_C     786432     // [32]
#define WS_D     786464     // [32]

__device__ __forceinline__ float4 ld4(const float* __restrict__ p) {
    return *(const float4*)p;
}
__device__ __forceinline__ void st4(float* __restrict__ p, float4 v) {
    *(float4*)p = v;
}

// ---------------------------------------------------------------------------
// K1: per-row LN1 stats + u = xn @ W_in + b_in (stored transposed [b][r][s])
// 8 rows per block, W_in slice cached in registers (amortized over rows).
// ---------------------------------------------------------------------------
__global__ __launch_bounds__(256) void k1_ln_u(
    const float* __restrict__ x, const float* __restrict__ gamma,
    const float* __restrict__ beta, const float* __restrict__ Win,
    const float* __restrict__ b_in, float* __restrict__ ws)
{
    __shared__ float red[4][8];
    __shared__ float bcast[2];
    const int t = threadIdx.x;
    const int wv = t >> 6;
    const int row0 = blockIdx.x * 8;
    const int i0 = t * 8;               // fixed 8-element column slice

    // preload W_in[i0..i0+8)[0..8) : 64 contiguous floats, coalesced
    float win[64];
#pragma unroll
    for (int q = 0; q < 16; ++q) {
        float4 v = ld4(Win + i0 * 8 + q * 4);
        win[q*4+0] = v.x; win[q*4+1] = v.y; win[q*4+2] = v.z; win[q*4+3] = v.w;
    }
    float g[8], bt[8];
    {
        float4 a = ld4(gamma + i0), b = ld4(gamma + i0 + 4);
        g[0]=a.x; g[1]=a.y; g[2]=a.z; g[3]=a.w; g[4]=b.x; g[5]=b.y; g[6]=b.z; g[7]=b.w;
        a = ld4(beta + i0); b = ld4(beta + i0 + 4);
        bt[0]=a.x; bt[1]=a.y; bt[2]=a.z; bt[3]=a.w; bt[4]=b.x; bt[5]=b.y; bt[6]=b.z; bt[7]=b.w;
    }
    const int bb = row0 >> 12;          // batch
    const int s0 = row0 & 4095;         // seq pos of first row

    for (int rr = 0; rr < 8; ++rr) {
        const int row = row0 + rr;
        const float* xr = x + (size_t)row * D_MODEL + i0;
        float xv[8];
        {
            float4 a = ld4(xr), b = ld4(xr + 4);
            xv[0]=a.x; xv[1]=a.y; xv[2]=a.z; xv[3]=a.w;
            xv[4]=b.x; xv[5]=b.y; xv[6]=b.z; xv[7]=b.w;
        }
        float sum = 0.f, ssq = 0.f;
#pragma unroll
        for (int i = 0; i < 8; ++i) { sum += xv[i]; ssq = fmaf(xv[i], xv[i], ssq); }
#pragma unroll
        for (int off = 1; off < 64; off <<= 1) {
            sum += __shfl_xor(sum, off, 64);
            ssq += __shfl_xor(ssq, off, 64);
        }
        if ((t & 63) == 0) { red[wv][0] = sum; red[wv][1] = ssq; }
        __syncthreads();
        if (t == 0) {
            float s_ = red[0][0] + red[1][0] + red[2][0] + red[3][0];
            float q_ = red[0][1] + red[1][1] + red[2][1] + red[3][1];
            float mu = s_ * (1.f / D_MODEL);
            float var = q_ * (1.f / D_MODEL) - mu * mu;
            float rs = rsqrtf(var + EPSF);
            bcast[0] = mu; bcast[1] = rs;
            ws[WS_MU1 + row] = mu;
            ws[WS_RSIG1 + row] = rs;
        }
        __syncthreads();
        const float mu = bcast[0], rs = bcast[1];
        float up[8] = {0.f,0.f,0.f,0.f,0.f,0.f,0.f,0.f};
#pragma unroll
        for (int i = 0; i < 8; ++i) {
            const float xn = fmaf((xv[i] - mu) * rs, g[i], bt[i]);
#pragma unroll
            for (int j = 0; j < 8; ++j) up[j] = fmaf(xn, win[i*8 + j], up[j]);
        }
#pragma unroll
        for (int off = 1; off < 64; off <<= 1) {
#pragma unroll
            for (int j = 0; j < 8; ++j) up[j] += __shfl_xor(up[j], off, 64);
        }
        if ((t & 63) == 0) {
#pragma unroll
            for (int j = 0; j < 8; ++j) red[wv][j] = up[j];
        }
        __syncthreads();
        if (t < 8) {
            float uv = red[0][t] + red[1][t] + red[2][t] + red[3][t] + b_in[t];
            ws[WS_UT + ((size_t)bb * 8 + t) * 4096 + s0 + rr] = uv;
        }
        __syncthreads();  // LDS reuse next row
    }
}

// ---------------------------------------------------------------------------
// K2: blocks 0..31  : decay scan per (b,r), in place over u (chunked + wave-KS)
//     blocks 32..39 : build gamma-folded W_down^T via LDS transpose
//     block  40     : c_j = sum_i gamma_i*Wd_ij ; d_j = sum_i beta_i*Wd_ij + bd_j
// ---------------------------------------------------------------------------
__global__ __launch_bounds__(64) void k2_scan_prep(
    const float* __restrict__ logit, const float* __restrict__ Wd,
    const float* __restrict__ gamma, const float* __restrict__ beta,
    const float* __restrict__ bd, float* __restrict__ ws)
{
    const int t = threadIdx.x;
    const int blk = blockIdx.x;
    if (blk < 32) {
        const int b = blk >> 3, r = blk & 7;
        const float a = 1.f / (1.f + expf(-logit[r]));
        float* u = ws + WS_UT + ((size_t)b * 8 + r) * 4096 + t * 64;
        float v[64];
#pragma unroll
        for (int q = 0; q < 16; ++q) {
            float4 w = ld4(u + q * 4);
            v[q*4]=w.x; v[q*4+1]=w.y; v[q*4+2]=w.z; v[q*4+3]=w.w;
        }
        // local inclusive scan with zero carry
        float c = 0.f;
#pragma unroll
        for (int k = 0; k < 64; ++k) { c = fmaf(a, c, v[k]); v[k] = c; }
        // wave Kogge-Stone over chunk totals, element (A=a^64, B=total)
        float A = a;
#pragma unroll
        for (int i = 0; i < 6; ++i) A *= A;   // a^64
        float Bv = c, Aa = A;
#pragma unroll
        for (int off = 1; off < 64; off <<= 1) {
            float Ap = __shfl_up(Aa, off, 64);
            float Bp = __shfl_up(Bv, off, 64);
            if (t >= off) { Bv = fmaf(Aa, Bp, Bv); Aa *= Ap; }
        }
        float P = __shfl_up(Bv, 1, 64);
        if (t == 0) P = 0.f;
        // h_k = local_k + P * a^(k+1)
        float f = a * P;
#pragma unroll
        for (int k = 0; k < 64; ++k) { v[k] += f; f *= a; }
#pragma unroll
        for (int q = 0; q < 16; ++q)
            st4(u + q * 4, make_float4(v[q*4], v[q*4+1], v[q*4+2], v[q*4+3]));
    } else if (blk < 40) {
        __shared__ float tile[64 * 33];
        const int gblk = blk - 32;          // i-range [gblk*256, gblk*256+256)
        for (int cc = 0; cc < 4; ++cc) {
            const int ibase = gblk * 256 + cc * 64;
#pragma unroll
            for (int m = 0; m < 32; ++m) {
                const int e = m * 64 + t;   // linear within 64x32 chunk, coalesced
                const int il = e >> 5, j = e & 31;
                tile[il * 33 + j] = Wd[(size_t)ibase * 32 + e];
            }
            __syncthreads();
#pragma unroll
            for (int j = 0; j < 32; ++j) {
                const int i = ibase + t;
                ws[WS_WDT + (size_t)j * 2048 + i] = gamma[i] * tile[t * 33 + j];
            }
            __syncthreads();
        }
    } else {
        const int j = t & 31, h = t >> 5;
        float cacc = 0.f, dacc = 0.f;
        for (int k = 0; k < 1024; ++k) {
            const int i = h * 1024 + k;
            const float w = Wd[(size_t)i * 32 + j];
            cacc = fmaf(gamma[i], w, cacc);
            dacc = fmaf(beta[i], w, dacc);
        }
        cacc += __shfl_xor(cacc, 32, 64);
        dacc += __shfl_xor(dacc, 32, 64);
        if (t < 32) {
            ws[WS_C + j] = cacc;
            ws[WS_D + j] = dacc + bd[j];
        }
    }
}

// ---------------------------------------------------------------------------
// K3a: 8 rows/block. Phase A: x2 = x + h@Wout + b_out + xn*D_skip -> d_out,
// LN2 stats, x2 staged to LDS. Phase B: praw[r][j] = sum_i x2*gamma*Wd  via
// 8x8 register tile (dense LDS reads, coalesced WdT reads), lane reduce via
// rotated-LDS transpose (reusing Y).
// ---------------------------------------------------------------------------
__global__ __launch_bounds__(256) void k3a_ar_p(
    const float* __restrict__ x, const float* __restrict__ gamma,
    const float* __restrict__ beta, const float* __restrict__ Wout,
    const float* __restrict__ b_out, const float* __restrict__ Dsk,
    float* __restrict__ out, float* __restrict__ ws)
{
    __shared__ float Y[8 * 2048];   // 64 KiB
    const int t = threadIdx.x;
    const int blk = blockIdx.x;
    const int r = t >> 5, l = t & 31;
    const int row = blk * 8 + r;
    const int bb = row >> 12, s = row & 4095;
    const float mu1 = ws[WS_MU1 + row], rs1 = ws[WS_RSIG1 + row];
    float h[8];
#pragma unroll
    for (int j = 0; j < 8; ++j)
        h[j] = ws[WS_UT + ((size_t)bb * 8 + j) * 4096 + s];
    const float* xr = x + (size_t)row * D_MODEL;
    float* orow = out + (size_t)row * D_MODEL;
    float sum = 0.f, ssq = 0.f;
#pragma unroll 2
    for (int k = 0; k < 16; ++k) {
        const int i = k * 128 + l * 4;
        float4 xv = ld4(xr + i);
        float4 gv = ld4(gamma + i), bv = ld4(beta + i);
        float4 bo = ld4(b_out + i), dk = ld4(Dsk + i);
        float4 acc = bo;
#pragma unroll
        for (int j = 0; j < 8; ++j) {
            float4 w = ld4(Wout + (size_t)j * D_MODEL + i);
            acc.x = fmaf(h[j], w.x, acc.x);
            acc.y = fmaf(h[j], w.y, acc.y);
            acc.z = fmaf(h[j], w.z, acc.z);
            acc.w = fmaf(h[j], w.w, acc.w);
        }
        float4 xn;
        xn.x = fmaf((xv.x - mu1) * rs1, gv.x, bv.x);
        xn.y = fmaf((xv.y - mu1) * rs1, gv.y, bv.y);
        xn.z = fmaf((xv.z - mu1) * rs1, gv.z, bv.z);
        xn.w = fmaf((xv.w - mu1) * rs1, gv.w, bv.w);
        acc.x = fmaf(xn.x, dk.x, acc.x);
        acc.y = fmaf(xn.y, dk.y, acc.y);
        acc.z = fmaf(xn.z, dk.z, acc.z);
        acc.w = fmaf(xn.w, dk.w, acc.w);
        float4 x2;
        x2.x = xv.x + acc.x; x2.y = xv.y + acc.y;
        x2.z = xv.z + acc.z; x2.w = xv.w + acc.w;
        st4(orow + i, x2);
        st4(&Y[r * 2048 + i], x2);
        sum += x2.x + x2.y + x2.z + x2.w;
        ssq = fmaf(x2.x, x2.x, ssq); ssq = fmaf(x2.y, x2.y, ssq);
        ssq = fmaf(x2.z, x2.z, ssq); ssq = fmaf(x2.w, x2.w, ssq);
    }
    // LN2 stats: reduce across the 32 lanes of this row-group (half-wave)
#pragma unroll
    for (int off = 1; off < 32; off <<= 1) {
        sum += __shfl_xor(sum, off, 64);
        ssq += __shfl_xor(ssq, off, 64);
    }
    if (l == 0) {
        const float mu2 = sum * (1.f / D_MODEL);
        const float var = ssq * (1.f / D_MODEL) - mu2 * mu2;
        ws[WS_MU2 + row] = mu2;
        ws[WS_RSIG2 + row] = rsqrtf(var + EPSF);
    }
    __syncthreads();

    // Phase B: wave w owns j-octet [8w, 8w+8); 8 rows x 8 cols register tile
    const int wvb = t >> 6, lane = t & 63;
    const int jb = wvb * 8;
    float p[64];
#pragma unroll
    for (int v = 0; v < 64; ++v) p[v] = 0.f;
#pragma unroll 1
    for (int q = 0; q < 8; ++q) {
        const int ip = q * 256 + lane * 4;
        float4 yv[8];
#pragma unroll
        for (int rr = 0; rr < 8; ++rr) yv[rr] = ld4(&Y[rr * 2048 + ip]);
#pragma unroll
        for (int jj = 0; jj < 8; ++jj) {
            float4 w = ld4(ws + WS_WDT + (size_t)(jb + jj) * 2048 + ip);
#pragma unroll
            for (int rr = 0; rr < 8; ++rr) {
                p[rr*8+jj] = fmaf(yv[rr].x, w.x, p[rr*8+jj]);
                p[rr*8+jj] = fmaf(yv[rr].y, w.y, p[rr*8+jj]);
                p[rr*8+jj] = fmaf(yv[rr].z, w.z, p[rr*8+jj]);
                p[rr*8+jj] = fmaf(yv[rr].w, w.w, p[rr*8+jj]);
            }
        }
    }
    __syncthreads();   // all waves done reading Y; now reuse as scratch
    float* scratch = &Y[wvb * 4096];   // 16 KiB per wave, private
#pragma unroll
    for (int v = 0; v < 64; ++v)
        scratch[lane * 64 + ((v + lane) & 63)] = p[v];   // rotated: conflict-free
    __syncthreads();
    float tot = 0.f;
    for (int s2 = 0; s2 < 64; ++s2)
        tot += scratch[s2 * 64 + ((lane + s2) & 63)];
    const int orr = lane >> 3, ojj = lane & 7;
    ws[WS_PRAW + (size_t)(blk * 8 + orr) * 32 + jb + ojj] = tot;
}

// ---------------------------------------------------------------------------
// K3b: 32 rows/block. hf = relu(rs2*(praw - mu2*c) + d) ; out = x2 + hf@Wu + bu
// Wu is [32][2048] (row-major) -> naturally coalesced; hf in registers.
// ---------------------------------------------------------------------------
__global__ __launch_bounds__(256) void k3b_ffn(
    const float* __restrict__ Wu, const float* __restrict__ bu,
    const float* __restrict__ ws, float* __restrict__ out)
{
    __shared__ float hf[32 * 32];
    const int t = threadIdx.x;
    const int blk = blockIdx.x;
    const int row0 = blk * 32;
    {
        const int rr = t >> 3, jq = (t & 7) * 4;
        const int row = row0 + rr;
        const float mu2 = ws[WS_MU2 + row], rs2 = ws[WS_RSIG2 + row];
        float4 p = ld4(ws + WS_PRAW + (size_t)row * 32 + jq);
        float4 c = ld4(ws + WS_C + jq);
        float4 dv = ld4(ws + WS_D + jq);
        float4 v;
        v.x = fmaxf(0.f, fmaf(rs2, fmaf(-mu2, c.x, p.x), dv.x));
        v.y = fmaxf(0.f, fmaf(rs2, fmaf(-mu2, c.y, p.y), dv.y));
        v.z = fmaxf(0.f, fmaf(rs2, fmaf(-mu2, c.z, p.z), dv.z));
        v.w = fmaxf(0.f, fmaf(rs2, fmaf(-mu2, c.w, p.w), dv.w));
        st4(&hf[rr * 32 + jq], v);
    }
    __syncthreads();
    const int r = t >> 3, l = t & 7;
    const int row = row0 + r;
    float hfr[32];
#pragma unroll
    for (int q = 0; q < 8; ++q) {
        float4 v = ld4(&hf[r * 32 + q * 4]);
        hfr[q*4]=v.x; hfr[q*4+1]=v.y; hfr[q*4+2]=v.z; hfr[q*4+3]=v.w;
    }
    float* orow = out + (size_t)row * D_MODEL;
#pragma unroll 2
    for (int k = 0; k < 64; ++k) {
        const int i = k * 32 + l * 4;
        float4 acc = ld4(bu + i);
        float4 x2 = ld4(orow + i);
        acc.x += x2.x; acc.y += x2.y; acc.z += x2.z; acc.w += x2.w;
#pragma unroll
        for (int j = 0; j < 32; ++j) {
            float4 w = ld4(Wu + (size_t)j * D_MODEL + i);
            acc.x = fmaf(hfr[j], w.x, acc.x);
            acc.y = fmaf(hfr[j], w.y, acc.y);
            acc.z = fmaf(hfr[j], w.z, acc.z);
            acc.w = fmaf(hfr[j], w.w, acc.w);
        }
        st4(orow + i, acc);
    }
}

// ---------------------------------------------------------------------------
extern "C" void kernel_launch(void* const* d_in, const int* in_sizes, int n_in,
                              void* d_out, int out_size, void* d_ws, size_t ws_size,
                              hipStream_t stream) {
    const float* x      = (const float*)d_in[0];
    const float* gamma  = (const float*)d_in[1];
    const float* beta   = (const float*)d_in[2];
    const float* Win    = (const float*)d_in[3];
    const float* b_in   = (const float*)d_in[4];
    const float* logit  = (const float*)d_in[5];
    const float* Wout   = (const float*)d_in[6];
    const float* b_out  = (const float*)d_in[7];
    const float* Dsk    = (const float*)d_in[8];
    const float* Wd     = (const float*)d_in[9];
    const float* bd     = (const float*)d_in[10];
    const float* Wu     = (const float*)d_in[11];
    const float* bu     = (const float*)d_in[12];
    float* out = (float*)d_out;
    float* ws  = (float*)d_ws;

    hipLaunchKernelGGL(k1_ln_u,     dim3(2048), dim3(256), 0, stream,
                       x, gamma, beta, Win, b_in, ws);
    hipLaunchKernelGGL(k2_scan_prep, dim3(41),  dim3(64),  0, stream,
                       logit, Wd, gamma, beta, bd, ws);
    hipLaunchKernelGGL(k3a_ar_p,    dim3(2048), dim3(256), 0, stream,
                       x, gamma, beta, Wout, b_out, Dsk, out, ws);
    hipLaunchKernelGGL(k3b_ffn,     dim3(512),  dim3(256), 0, stream,
                       Wu, bu, ws, out);
}

// Round 2
// 642.620 us; speedup vs baseline: 1.3305x; 1.3305x over previous
//
#include <hip/hip_runtime.h>
#include <cstdint>
#include <cstddef>

#define D_MODEL 2048
#define EPSF 1e-5f

// workspace layout (float offsets)
#define WS_UT    0          // u/h transposed [4][8][4096] = 131072
#define WS_MU1   131072     // [16384]
#define WS_RSIG1 147456     // [16384]
#define WS_MU2   163840     // [16384]  (unused now)
#define WS_RSIG2 180224     // [16384]  (unused now)
#define WS_HF    196608     // hf [16384][32] = 524288  (post-ReLU FFN hidden)
#define WS_WDT   720896     // gamma-folded W_down^T [32][2048] = 65536
#define WS_C     786432     // [32]
#define WS_D     786464     // [32]

__device__ __forceinline__ float4 ld4(const float* __restrict__ p) {
    return *(const float4*)p;
}
__device__ __forceinline__ void st4(float* __restrict__ p, float4 v) {
    *(float4*)p = v;
}

// ---------------------------------------------------------------------------
// K1: per-row LN1 stats + u = xn @ W_in + b_in (stored transposed [b][r][s])
// 8 rows per block, W_in slice cached in registers (amortized over rows).
// ---------------------------------------------------------------------------
__global__ __launch_bounds__(256) void k1_ln_u(
    const float* __restrict__ x, const float* __restrict__ gamma,
    const float* __restrict__ beta, const float* __restrict__ Win,
    const float* __restrict__ b_in, float* __restrict__ ws)
{
    __shared__ float red[4][8];
    __shared__ float bcast[2];
    const int t = threadIdx.x;
    const int wv = t >> 6;
    const int row0 = blockIdx.x * 8;
    const int i0 = t * 8;               // fixed 8-element column slice

    // preload W_in[i0..i0+8)[0..8) : 64 contiguous floats, coalesced
    float win[64];
#pragma unroll
    for (int q = 0; q < 16; ++q) {
        float4 v = ld4(Win + i0 * 8 + q * 4);
        win[q*4+0] = v.x; win[q*4+1] = v.y; win[q*4+2] = v.z; win[q*4+3] = v.w;
    }
    float g[8], bt[8];
    {
        float4 a = ld4(gamma + i0), b = ld4(gamma + i0 + 4);
        g[0]=a.x; g[1]=a.y; g[2]=a.z; g[3]=a.w; g[4]=b.x; g[5]=b.y; g[6]=b.z; g[7]=b.w;
        a = ld4(beta + i0); b = ld4(beta + i0 + 4);
        bt[0]=a.x; bt[1]=a.y; bt[2]=a.z; bt[3]=a.w; bt[4]=b.x; bt[5]=b.y; bt[6]=b.z; bt[7]=b.w;
    }
    const int bb = row0 >> 12;          // batch
    const int s0 = row0 & 4095;         // seq pos of first row

    for (int rr = 0; rr < 8; ++rr) {
        const int row = row0 + rr;
        const float* xr = x + (size_t)row * D_MODEL + i0;
        float xv[8];
        {
            float4 a = ld4(xr), b = ld4(xr + 4);
            xv[0]=a.x; xv[1]=a.y; xv[2]=a.z; xv[3]=a.w;
            xv[4]=b.x; xv[5]=b.y; xv[6]=b.z; xv[7]=b.w;
        }
        float sum = 0.f, ssq = 0.f;
#pragma unroll
        for (int i = 0; i < 8; ++i) { sum += xv[i]; ssq = fmaf(xv[i], xv[i], ssq); }
#pragma unroll
        for (int off = 1; off < 64; off <<= 1) {
            sum += __shfl_xor(sum, off, 64);
            ssq += __shfl_xor(ssq, off, 64);
        }
        if ((t & 63) == 0) { red[wv][0] = sum; red[wv][1] = ssq; }
        __syncthreads();
        if (t == 0) {
            float s_ = red[0][0] + red[1][0] + red[2][0] + red[3][0];
            float q_ = red[0][1] + red[1][1] + red[2][1] + red[3][1];
            float mu = s_ * (1.f / D_MODEL);
            float var = q_ * (1.f / D_MODEL) - mu * mu;
            float rs = rsqrtf(var + EPSF);
            bcast[0] = mu; bcast[1] = rs;
            ws[WS_MU1 + row] = mu;
            ws[WS_RSIG1 + row] = rs;
        }
        __syncthreads();
        const float mu = bcast[0], rs = bcast[1];
        float up[8] = {0.f,0.f,0.f,0.f,0.f,0.f,0.f,0.f};
#pragma unroll
        for (int i = 0; i < 8; ++i) {
            const float xn = fmaf((xv[i] - mu) * rs, g[i], bt[i]);
#pragma unroll
            for (int j = 0; j < 8; ++j) up[j] = fmaf(xn, win[i*8 + j], up[j]);
        }
#pragma unroll
        for (int off = 1; off < 64; off <<= 1) {
#pragma unroll
            for (int j = 0; j < 8; ++j) up[j] += __shfl_xor(up[j], off, 64);
        }
        if ((t & 63) == 0) {
#pragma unroll
            for (int j = 0; j < 8; ++j) red[wv][j] = up[j];
        }
        __syncthreads();
        if (t < 8) {
            float uv = red[0][t] + red[1][t] + red[2][t] + red[3][t] + b_in[t];
            ws[WS_UT + ((size_t)bb * 8 + t) * 4096 + s0 + rr] = uv;
        }
        __syncthreads();  // LDS reuse next row
    }
}

// ---------------------------------------------------------------------------
// K2: blocks 0..31  : decay scan per (b,r), in place over u (chunked + wave-KS)
//     blocks 32..39 : build gamma-folded W_down^T via LDS transpose
//     block  40     : c_j = sum_i gamma_i*Wd_ij ; d_j = sum_i beta_i*Wd_ij + bd_j
// ---------------------------------------------------------------------------
__global__ __launch_bounds__(64) void k2_scan_prep(
    const float* __restrict__ logit, const float* __restrict__ Wd,
    const float* __restrict__ gamma, const float* __restrict__ beta,
    const float* __restrict__ bd, float* __restrict__ ws)
{
    const int t = threadIdx.x;
    const int blk = blockIdx.x;
    if (blk < 32) {
        const int b = blk >> 3, r = blk & 7;
        const float a = 1.f / (1.f + expf(-logit[r]));
        float* u = ws + WS_UT + ((size_t)b * 8 + r) * 4096 + t * 64;
        float v[64];
#pragma unroll
        for (int q = 0; q < 16; ++q) {
            float4 w = ld4(u + q * 4);
            v[q*4]=w.x; v[q*4+1]=w.y; v[q*4+2]=w.z; v[q*4+3]=w.w;
        }
        // local inclusive scan with zero carry
        float c = 0.f;
#pragma unroll
        for (int k = 0; k < 64; ++k) { c = fmaf(a, c, v[k]); v[k] = c; }
        // wave Kogge-Stone over chunk totals, element (A=a^64, B=total)
        float A = a;
#pragma unroll
        for (int i = 0; i < 6; ++i) A *= A;   // a^64
        float Bv = c, Aa = A;
#pragma unroll
        for (int off = 1; off < 64; off <<= 1) {
            float Ap = __shfl_up(Aa, off, 64);
            float Bp = __shfl_up(Bv, off, 64);
            if (t >= off) { Bv = fmaf(Aa, Bp, Bv); Aa *= Ap; }
        }
        float P = __shfl_up(Bv, 1, 64);
        if (t == 0) P = 0.f;
        // h_k = local_k + P * a^(k+1)
        float f = a * P;
#pragma unroll
        for (int k = 0; k < 64; ++k) { v[k] += f; f *= a; }
#pragma unroll
        for (int q = 0; q < 16; ++q)
            st4(u + q * 4, make_float4(v[q*4], v[q*4+1], v[q*4+2], v[q*4+3]));
    } else if (blk < 40) {
        __shared__ float tile[64 * 33];
        const int gblk = blk - 32;          // i-range [gblk*256, gblk*256+256)
        for (int cc = 0; cc < 4; ++cc) {
            const int ibase = gblk * 256 + cc * 64;
#pragma unroll
            for (int m = 0; m < 32; ++m) {
                const int e = m * 64 + t;   // linear within 64x32 chunk, coalesced
                const int il = e >> 5, j = e & 31;
                tile[il * 33 + j] = Wd[(size_t)ibase * 32 + e];
            }
            __syncthreads();
#pragma unroll
            for (int j = 0; j < 32; ++j) {
                const int i = ibase + t;
                ws[WS_WDT + (size_t)j * 2048 + i] = gamma[i] * tile[t * 33 + j];
            }
            __syncthreads();
        }
    } else {
        const int j = t & 31, h = t >> 5;
        float cacc = 0.f, dacc = 0.f;
        for (int k = 0; k < 1024; ++k) {
            const int i = h * 1024 + k;
            const float w = Wd[(size_t)i * 32 + j];
            cacc = fmaf(gamma[i], w, cacc);
            dacc = fmaf(beta[i], w, dacc);
        }
        cacc += __shfl_xor(cacc, 32, 64);
        dacc += __shfl_xor(dacc, 32, 64);
        if (t < 32) {
            ws[WS_C + j] = cacc;
            ws[WS_D + j] = dacc + bd[j];
        }
    }
}

// ---------------------------------------------------------------------------
// K3a: 8 rows/block. Phase A: x2 = x + h@Wout + b_out + xn*D_skip -> d_out,
// LN2 stats (kept in LDS), x2 staged to LDS. Phase B: praw[r][j] via 8x8
// register tile; epilogue applies LN2 affine transform + ReLU and stores hf.
// ---------------------------------------------------------------------------
__global__ __launch_bounds__(256) void k3a_ar_p(
    const float* __restrict__ x, const float* __restrict__ gamma,
    const float* __restrict__ beta, const float* __restrict__ Wout,
    const float* __restrict__ b_out, const float* __restrict__ Dsk,
    float* __restrict__ out, float* __restrict__ ws)
{
    __shared__ float Y[8 * 2048];   // 64 KiB
    __shared__ float smu2[8], srs2[8];
    const int t = threadIdx.x;
    const int blk = blockIdx.x;
    const int r = t >> 5, l = t & 31;
    const int row = blk * 8 + r;
    const int bb = row >> 12, s = row & 4095;
    const float mu1 = ws[WS_MU1 + row], rs1 = ws[WS_RSIG1 + row];
    float h[8];
#pragma unroll
    for (int j = 0; j < 8; ++j)
        h[j] = ws[WS_UT + ((size_t)bb * 8 + j) * 4096 + s];
    const float* xr = x + (size_t)row * D_MODEL;
    float* orow = out + (size_t)row * D_MODEL;
    float sum = 0.f, ssq = 0.f;
#pragma unroll 2
    for (int k = 0; k < 16; ++k) {
        const int i = k * 128 + l * 4;
        float4 xv = ld4(xr + i);
        float4 gv = ld4(gamma + i), bv = ld4(beta + i);
        float4 bo = ld4(b_out + i), dk = ld4(Dsk + i);
        float4 acc = bo;
#pragma unroll
        for (int j = 0; j < 8; ++j) {
            float4 w = ld4(Wout + (size_t)j * D_MODEL + i);
            acc.x = fmaf(h[j], w.x, acc.x);
            acc.y = fmaf(h[j], w.y, acc.y);
            acc.z = fmaf(h[j], w.z, acc.z);
            acc.w = fmaf(h[j], w.w, acc.w);
        }
        float4 xn;
        xn.x = fmaf((xv.x - mu1) * rs1, gv.x, bv.x);
        xn.y = fmaf((xv.y - mu1) * rs1, gv.y, bv.y);
        xn.z = fmaf((xv.z - mu1) * rs1, gv.z, bv.z);
        xn.w = fmaf((xv.w - mu1) * rs1, gv.w, bv.w);
        acc.x = fmaf(xn.x, dk.x, acc.x);
        acc.y = fmaf(xn.y, dk.y, acc.y);
        acc.z = fmaf(xn.z, dk.z, acc.z);
        acc.w = fmaf(xn.w, dk.w, acc.w);
        float4 x2;
        x2.x = xv.x + acc.x; x2.y = xv.y + acc.y;
        x2.z = xv.z + acc.z; x2.w = xv.w + acc.w;
        st4(orow + i, x2);
        st4(&Y[r * 2048 + i], x2);
        sum += x2.x + x2.y + x2.z + x2.w;
        ssq = fmaf(x2.x, x2.x, ssq); ssq = fmaf(x2.y, x2.y, ssq);
        ssq = fmaf(x2.z, x2.z, ssq); ssq = fmaf(x2.w, x2.w, ssq);
    }
    // LN2 stats: reduce across the 32 lanes of this row-group (half-wave)
#pragma unroll
    for (int off = 1; off < 32; off <<= 1) {
        sum += __shfl_xor(sum, off, 64);
        ssq += __shfl_xor(ssq, off, 64);
    }
    if (l == 0) {
        const float mu2 = sum * (1.f / D_MODEL);
        const float var = ssq * (1.f / D_MODEL) - mu2 * mu2;
        smu2[r] = mu2;
        srs2[r] = rsqrtf(var + EPSF);
    }
    __syncthreads();

    // Phase B: wave w owns j-octet [8w, 8w+8); 8 rows x 8 cols register tile
    const int wvb = t >> 6, lane = t & 63;
    const int jb = wvb * 8;
    float p[64];
#pragma unroll
    for (int v = 0; v < 64; ++v) p[v] = 0.f;
#pragma unroll 1
    for (int q = 0; q < 8; ++q) {
        const int ip = q * 256 + lane * 4;
        float4 yv[8];
#pragma unroll
        for (int rr = 0; rr < 8; ++rr) yv[rr] = ld4(&Y[rr * 2048 + ip]);
#pragma unroll
        for (int jj = 0; jj < 8; ++jj) {
            float4 w = ld4(ws + WS_WDT + (size_t)(jb + jj) * 2048 + ip);
#pragma unroll
            for (int rr = 0; rr < 8; ++rr) {
                p[rr*8+jj] = fmaf(yv[rr].x, w.x, p[rr*8+jj]);
                p[rr*8+jj] = fmaf(yv[rr].y, w.y, p[rr*8+jj]);
                p[rr*8+jj] = fmaf(yv[rr].z, w.z, p[rr*8+jj]);
                p[rr*8+jj] = fmaf(yv[rr].w, w.w, p[rr*8+jj]);
            }
        }
    }
    __syncthreads();   // all waves done reading Y; now reuse as scratch
    float* scratch = &Y[wvb * 4096];   // 16 KiB per wave, private
#pragma unroll
    for (int v = 0; v < 64; ++v)
        scratch[lane * 64 + ((v + lane) & 63)] = p[v];   // rotated: conflict-free
    __syncthreads();
    float tot = 0.f;
    for (int s2 = 0; s2 < 64; ++s2)
        tot += scratch[s2 * 64 + ((lane + s2) & 63)];
    const int orr = lane >> 3, ojj = lane & 7;
    // fused LN2 transform + ReLU -> hf
    const float mu2r = smu2[orr], rs2r = srs2[orr];
    const float cj = ws[WS_C + jb + ojj], dj = ws[WS_D + jb + ojj];
    const float hf = fmaxf(0.f, fmaf(rs2r, fmaf(-mu2r, cj, tot), dj));
    ws[WS_HF + (size_t)(blk * 8 + orr) * 32 + jb + ojj] = hf;
}

// ---------------------------------------------------------------------------
// K3b: register-resident rank-32 up-projection streamer.
// Each thread owns 4 consecutive columns; caches Wu[0..32)[col..col+4) in
// 128 VGPRs once, then streams 64 rows: out = x2 + bu + hf @ Wu.
// hf[row][32] fetched as wave-uniform float4 broadcasts (no LDS, no barriers).
// ---------------------------------------------------------------------------
__global__ __launch_bounds__(256, 2) void k3b_ffn(
    const float* __restrict__ Wu, const float* __restrict__ bu,
    const float* __restrict__ ws, float* __restrict__ out)
{
    const int t = threadIdx.x;
    const int cg = blockIdx.x & 1;           // column group (0 -> cols 0..1023)
    const int rb = blockIdx.x >> 1;          // row block 0..255
    const int col = cg * 1024 + t * 4;

    float4 w[32];
#pragma unroll
    for (int j = 0; j < 32; ++j) w[j] = ld4(Wu + (size_t)j * D_MODEL + col);
    const float4 bub = ld4(bu + col);

    const int row0 = rb * 64;
#pragma unroll 1
    for (int rr = 0; rr < 64; rr += 2) {
        const int row = row0 + rr;
        const float* hfp = ws + WS_HF + (size_t)row * 32;
        float* o0 = out + (size_t)row * D_MODEL + col;
        float* o1 = o0 + D_MODEL;
        float4 hv0[8], hv1[8];
#pragma unroll
        for (int q = 0; q < 8; ++q) {
            hv0[q] = ld4(hfp + q * 4);
            hv1[q] = ld4(hfp + 32 + q * 4);
        }
        float4 a0 = ld4(o0), a1 = ld4(o1);
        a0.x += bub.x; a0.y += bub.y; a0.z += bub.z; a0.w += bub.w;
        a1.x += bub.x; a1.y += bub.y; a1.z += bub.z; a1.w += bub.w;
#pragma unroll
        for (int q = 0; q < 8; ++q) {
            const float h00 = hv0[q].x, h01 = hv0[q].y, h02 = hv0[q].z, h03 = hv0[q].w;
            const float h10 = hv1[q].x, h11 = hv1[q].y, h12 = hv1[q].z, h13 = hv1[q].w;
            const float4 w0 = w[q*4+0], w1 = w[q*4+1], w2 = w[q*4+2], w3 = w[q*4+3];
            a0.x = fmaf(h00, w0.x, a0.x); a0.y = fmaf(h00, w0.y, a0.y);
            a0.z = fmaf(h00, w0.z, a0.z); a0.w = fmaf(h00, w0.w, a0.w);
            a0.x = fmaf(h01, w1.x, a0.x); a0.y = fmaf(h01, w1.y, a0.y);
            a0.z = fmaf(h01, w1.z, a0.z); a0.w = fmaf(h01, w1.w, a0.w);
            a0.x = fmaf(h02, w2.x, a0.x); a0.y = fmaf(h02, w2.y, a0.y);
            a0.z = fmaf(h02, w2.z, a0.z); a0.w = fmaf(h02, w2.w, a0.w);
            a0.x = fmaf(h03, w3.x, a0.x); a0.y = fmaf(h03, w3.y, a0.y);
            a0.z = fmaf(h03, w3.z, a0.z); a0.w = fmaf(h03, w3.w, a0.w);
            a1.x = fmaf(h10, w0.x, a1.x); a1.y = fmaf(h10, w0.y, a1.y);
            a1.z = fmaf(h10, w0.z, a1.z); a1.w = fmaf(h10, w0.w, a1.w);
            a1.x = fmaf(h11, w1.x, a1.x); a1.y = fmaf(h11, w1.y, a1.y);
            a1.z = fmaf(h11, w1.z, a1.z); a1.w = fmaf(h11, w1.w, a1.w);
            a1.x = fmaf(h12, w2.x, a1.x); a1.y = fmaf(h12, w2.y, a1.y);
            a1.z = fmaf(h12, w2.z, a1.z); a1.w = fmaf(h12, w2.w, a1.w);
            a1.x = fmaf(h13, w3.x, a1.x); a1.y = fmaf(h13, w3.y, a1.y);
            a1.z = fmaf(h13, w3.z, a1.z); a1.w = fmaf(h13, w3.w, a1.w);
        }
        st4(o0, a0);
        st4(o1, a1);
    }
}

// ---------------------------------------------------------------------------
extern "C" void kernel_launch(void* const* d_in, const int* in_sizes, int n_in,
                              void* d_out, int out_size, void* d_ws, size_t ws_size,
                              hipStream_t stream) {
    const float* x      = (const float*)d_in[0];
    const float* gamma  = (const float*)d_in[1];
    const float* beta   = (const float*)d_in[2];
    const float* Win    = (const float*)d_in[3];
    const float* b_in   = (const float*)d_in[4];
    const float* logit  = (const float*)d_in[5];
    const float* Wout   = (const float*)d_in[6];
    const float* b_out  = (const float*)d_in[7];
    const float* Dsk    = (const float*)d_in[8];
    const float* Wd     = (const float*)d_in[9];
    const float* bd     = (const float*)d_in[10];
    const float* Wu     = (const float*)d_in[11];
    const float* bu     = (const float*)d_in[12];
    float* out = (float*)d_out;
    float* ws  = (float*)d_ws;

    hipLaunchKernelGGL(k1_ln_u,     dim3(2048), dim3(256), 0, stream,
                       x, gamma, beta, Win, b_in, ws);
    hipLaunchKernelGGL(k2_scan_prep, dim3(41),  dim3(64),  0, stream,
                       logit, Wd, gamma, beta, bd, ws);
    hipLaunchKernelGGL(k3a_ar_p,    dim3(2048), dim3(256), 0, stream,
                       x, gamma, beta, Wout, b_out, Dsk, out, ws);
    hipLaunchKernelGGL(k3b_ffn,     dim3(512),  dim3(256), 0, stream,
                       Wu, bu, ws, out);
}

// Round 3
// 496.905 us; speedup vs baseline: 1.7206x; 1.2932x over previous
//
#include <hip/hip_runtime.h>
#include <cstdint>
#include <cstddef>

#define D_MODEL 2048
#define EPSF 1e-5f

// workspace layout (float offsets)
#define WS_UT    0          // u/h transposed [4][8][4096] = 131072
#define WS_MU1   131072     // [16384]
#define WS_RSIG1 147456     // [16384]
#define WS_WDT   163840     // gamma-folded W_down^T [32][2048] = 65536
#define WS_WINF  229376     // gamma-folded W_in [2048][8] = 16384
#define WS_C     245760     // [32]  col-sums gamma*Wd
#define WS_D     245792     // [32]  col-sums beta*Wd + bd
#define WS_CIN   245824     // [8]   col-sums gamma*Win
#define WS_DIN   245832     // [8]   col-sums beta*Win + b_in

__device__ __forceinline__ float4 ld4(const float* __restrict__ p) {
    return *(const float4*)p;
}
__device__ __forceinline__ void st4(float* __restrict__ p, float4 v) {
    *(float4*)p = v;
}
__device__ __forceinline__ int bitrev6(int l) {
    return ((l & 1) << 5) | ((l & 2) << 3) | ((l & 4) << 1) |
           ((l & 8) >> 1) | ((l & 16) >> 3) | ((l & 32) >> 5);
}
__device__ __forceinline__ int bitrev4(int l) {
    return ((l & 1) << 3) | ((l & 2) << 1) | ((l & 4) >> 1) | ((l & 8) >> 3);
}

// ---------------------------------------------------------------------------
// K0: weight prep. blocks 0..7: gamma-folded W_down^T via LDS transpose.
// block 8: c/d col-sums for Wd. block 9: gamma-folded W_in + cin/din.
// ---------------------------------------------------------------------------
__global__ __launch_bounds__(64) void k0_prep(
    const float* __restrict__ Win, const float* __restrict__ b_in,
    const float* __restrict__ Wd, const float* __restrict__ gamma,
    const float* __restrict__ beta, const float* __restrict__ bd,
    float* __restrict__ ws)
{
    const int t = threadIdx.x;
    const int blk = blockIdx.x;
    if (blk < 8) {
        __shared__ float tile[64 * 33];
        const int gblk = blk;               // i-range [gblk*256, gblk*256+256)
        for (int cc = 0; cc < 4; ++cc) {
            const int ibase = gblk * 256 + cc * 64;
#pragma unroll
            for (int m = 0; m < 32; ++m) {
                const int e = m * 64 + t;   // linear within 64x32 chunk, coalesced
                const int il = e >> 5, j = e & 31;
                tile[il * 33 + j] = Wd[(size_t)ibase * 32 + e];
            }
            __syncthreads();
#pragma unroll
            for (int j = 0; j < 32; ++j) {
                const int i = ibase + t;
                ws[WS_WDT + (size_t)j * 2048 + i] = gamma[i] * tile[t * 33 + j];
            }
            __syncthreads();
        }
    } else if (blk == 8) {
        const int j = t & 31, h = t >> 5;
        float cacc = 0.f, dacc = 0.f;
        for (int k = 0; k < 1024; ++k) {
            const int i = h * 1024 + k;
            const float w = Wd[(size_t)i * 32 + j];
            cacc = fmaf(gamma[i], w, cacc);
            dacc = fmaf(beta[i], w, dacc);
        }
        cacc += __shfl_xor(cacc, 32, 64);
        dacc += __shfl_xor(dacc, 32, 64);
        if (t < 32) {
            ws[WS_C + j] = cacc;
            ws[WS_D + j] = dacc + bd[j];
        }
    } else {
        // fold Winf[i][j] = gamma_i * Win[i][j]; cin_j, din_j col-sums
        float cj[8], dj[8];
#pragma unroll
        for (int j = 0; j < 8; ++j) { cj[j] = 0.f; dj[j] = 0.f; }
        for (int k = 0; k < 32; ++k) {
            const int i = k * 64 + t;
            const float g = gamma[i], b = beta[i];
            float4 w0 = ld4(Win + (size_t)i * 8);
            float4 w1 = ld4(Win + (size_t)i * 8 + 4);
            st4(ws + WS_WINF + (size_t)i * 8,
                make_float4(g * w0.x, g * w0.y, g * w0.z, g * w0.w));
            st4(ws + WS_WINF + (size_t)i * 8 + 4,
                make_float4(g * w1.x, g * w1.y, g * w1.z, g * w1.w));
            cj[0] = fmaf(g, w0.x, cj[0]); cj[1] = fmaf(g, w0.y, cj[1]);
            cj[2] = fmaf(g, w0.z, cj[2]); cj[3] = fmaf(g, w0.w, cj[3]);
            cj[4] = fmaf(g, w1.x, cj[4]); cj[5] = fmaf(g, w1.y, cj[5]);
            cj[6] = fmaf(g, w1.z, cj[6]); cj[7] = fmaf(g, w1.w, cj[7]);
            dj[0] = fmaf(b, w0.x, dj[0]); dj[1] = fmaf(b, w0.y, dj[1]);
            dj[2] = fmaf(b, w0.z, dj[2]); dj[3] = fmaf(b, w0.w, dj[3]);
            dj[4] = fmaf(b, w1.x, dj[4]); dj[5] = fmaf(b, w1.y, dj[5]);
            dj[6] = fmaf(b, w1.z, dj[6]); dj[7] = fmaf(b, w1.w, dj[7]);
        }
#pragma unroll
        for (int off = 1; off < 64; off <<= 1) {
#pragma unroll
            for (int j = 0; j < 8; ++j) {
                cj[j] += __shfl_xor(cj[j], off, 64);
                dj[j] += __shfl_xor(dj[j], off, 64);
            }
        }
        if (t == 0) {
#pragma unroll
            for (int j = 0; j < 8; ++j) {
                ws[WS_CIN + j] = cj[j];
                ws[WS_DIN + j] = dj[j] + b_in[j];
            }
        }
    }
}

// ---------------------------------------------------------------------------
// K1: 8 rows/block. Raw dots uraw_j = x . (gamma*Win_col_j) plus sum/ssq in a
// single batched 16-value split-butterfly reduce per row (1 barrier total).
// u = rs1*(uraw - mu1*cin) + din, stored transposed [b][r][s].
// ---------------------------------------------------------------------------
__global__ __launch_bounds__(256) void k1_ln_u(
    const float* __restrict__ x, float* __restrict__ ws)
{
    __shared__ float red[8][4][12];
    const int t = threadIdx.x;
    const int wv = t >> 6, lane = t & 63;
    const int row0 = blockIdx.x * 8;
    const int i0 = t * 8;

    float winf[64];
#pragma unroll
    for (int q = 0; q < 16; ++q) {
        float4 v = ld4(ws + WS_WINF + (size_t)i0 * 8 + q * 4);
        winf[q*4+0] = v.x; winf[q*4+1] = v.y; winf[q*4+2] = v.z; winf[q*4+3] = v.w;
    }
    float xv[8][8];
#pragma unroll
    for (int rr = 0; rr < 8; ++rr) {
        const float* xr = x + (size_t)(row0 + rr) * D_MODEL + i0;
        float4 a = ld4(xr), b = ld4(xr + 4);
        xv[rr][0]=a.x; xv[rr][1]=a.y; xv[rr][2]=a.z; xv[rr][3]=a.w;
        xv[rr][4]=b.x; xv[rr][5]=b.y; xv[rr][6]=b.z; xv[rr][7]=b.w;
    }
#pragma unroll
    for (int rr = 0; rr < 8; ++rr) {
        float vals[16];
#pragma unroll
        for (int v = 0; v < 16; ++v) vals[v] = 0.f;
#pragma unroll
        for (int i = 0; i < 8; ++i) {
            const float xi = xv[rr][i];
            vals[0] += xi;
            vals[1] = fmaf(xi, xi, vals[1]);
#pragma unroll
            for (int j = 0; j < 8; ++j)
                vals[2+j] = fmaf(xi, winf[i*8 + j], vals[2+j]);
        }
        // 16-value split-butterfly over 64 lanes
        int count = 16;
#pragma unroll
        for (int step = 1; step <= 32; step <<= 1) {
            if (count > 1) {
                const int half = count >> 1;
                const bool up = (lane & step) != 0;
#pragma unroll
                for (int k = 0; k < 8; ++k) {
                    if (k < half) {
                        float send = vals[up ? k : k + half];
                        float keep = vals[up ? k + half : k];
                        vals[k] = keep + __shfl_xor(send, step, 64);
                    }
                }
                count = half;
            } else {
                vals[0] += __shfl_xor(vals[0], step, 64);
            }
        }
        if (lane < 16) {
            const int v = bitrev4(lane);
            if (v < 10) red[rr][wv][v] = vals[0];
        }
    }
    __syncthreads();
    if (t < 64) {
        const int row = t >> 3, j = t & 7;
        float s_ = 0.f, q_ = 0.f, uraw = 0.f;
#pragma unroll
        for (int w = 0; w < 4; ++w) {
            s_   += red[row][w][0];
            q_   += red[row][w][1];
            uraw += red[row][w][2 + j];
        }
        const float mu = s_ * (1.f / D_MODEL);
        const float var = q_ * (1.f / D_MODEL) - mu * mu;
        const float rs = rsqrtf(var + EPSF);
        const float u = fmaf(rs, fmaf(-mu, ws[WS_CIN + j], uraw), ws[WS_DIN + j]);
        const int grow = row0 + row;
        const int bb = grow >> 12, s0 = grow & 4095;
        ws[WS_UT + ((size_t)bb * 8 + j) * 4096 + s0] = u;
        if (j == 0) {
            ws[WS_MU1 + grow] = mu;
            ws[WS_RSIG1 + grow] = rs;
        }
    }
}

// ---------------------------------------------------------------------------
// K2: decay scan per (b,r), in place over u (chunked + wave Kogge-Stone)
// ---------------------------------------------------------------------------
__global__ __launch_bounds__(64) void k2_scan(
    const float* __restrict__ logit, float* __restrict__ ws)
{
    const int t = threadIdx.x;
    const int blk = blockIdx.x;
    const int b = blk >> 3, r = blk & 7;
    const float a = 1.f / (1.f + expf(-logit[r]));
    float* u = ws + WS_UT + ((size_t)b * 8 + r) * 4096 + t * 64;
    float v[64];
#pragma unroll
    for (int q = 0; q < 16; ++q) {
        float4 w = ld4(u + q * 4);
        v[q*4]=w.x; v[q*4+1]=w.y; v[q*4+2]=w.z; v[q*4+3]=w.w;
    }
    float c = 0.f;
#pragma unroll
    for (int k = 0; k < 64; ++k) { c = fmaf(a, c, v[k]); v[k] = c; }
    float A = a;
#pragma unroll
    for (int i = 0; i < 6; ++i) A *= A;   // a^64
    float Bv = c, Aa = A;
#pragma unroll
    for (int off = 1; off < 64; off <<= 1) {
        float Ap = __shfl_up(Aa, off, 64);
        float Bp = __shfl_up(Bv, off, 64);
        if (t >= off) { Bv = fmaf(Aa, Bp, Bv); Aa *= Ap; }
    }
    float P = __shfl_up(Bv, 1, 64);
    if (t == 0) P = 0.f;
    float f = a * P;
#pragma unroll
    for (int k = 0; k < 64; ++k) { v[k] += f; f *= a; }
#pragma unroll
    for (int q = 0; q < 16; ++q)
        st4(u + q * 4, make_float4(v[q*4], v[q*4+1], v[q*4+2], v[q*4+3]));
}

// ---------------------------------------------------------------------------
// K3: fully fused tail. 8 rows/block.
// Phase A: x2 = x + h@Wout + b_out + xn*D_skip -> LDS Y; LN2 stats.
// Phase B: praw = x2 @ (gamma*Wd) via 8x8 register tile; split-butterfly
//          lane reduce; fused LN2 affine + ReLU -> shf[8][32] in LDS.
// Phase C: out = x2 + bu + hf @ Wu  (Wu streamed from L2/L3; out written once).
// ---------------------------------------------------------------------------
__global__ __launch_bounds__(256) void k3_fused(
    const float* __restrict__ x, const float* __restrict__ gamma,
    const float* __restrict__ beta, const float* __restrict__ Wout,
    const float* __restrict__ b_out, const float* __restrict__ Dsk,
    const float* __restrict__ Wu, const float* __restrict__ bu,
    float* __restrict__ out, float* __restrict__ ws)
{
    __shared__ float Y[8 * 2048];   // 64 KiB: x2 rows
    __shared__ float shf[8 * 32];
    __shared__ float smu2[8], srs2[8];
    const int t = threadIdx.x;
    const int blk = blockIdx.x;
    const int r = t >> 5, l = t & 31;
    const int row = blk * 8 + r;
    const int bb = row >> 12, s = row & 4095;
    const float mu1 = ws[WS_MU1 + row], rs1 = ws[WS_RSIG1 + row];
    float h[8];
#pragma unroll
    for (int j = 0; j < 8; ++j)
        h[j] = ws[WS_UT + ((size_t)bb * 8 + j) * 4096 + s];
    const float* xr = x + (size_t)row * D_MODEL;
    float sum = 0.f, ssq = 0.f;
#pragma unroll 2
    for (int k = 0; k < 16; ++k) {
        const int i = k * 128 + l * 4;
        float4 xvv = ld4(xr + i);
        float4 gv = ld4(gamma + i), bv = ld4(beta + i);
        float4 bo = ld4(b_out + i), dk = ld4(Dsk + i);
        float4 acc = bo;
#pragma unroll
        for (int j = 0; j < 8; ++j) {
            float4 w = ld4(Wout + (size_t)j * D_MODEL + i);
            acc.x = fmaf(h[j], w.x, acc.x);
            acc.y = fmaf(h[j], w.y, acc.y);
            acc.z = fmaf(h[j], w.z, acc.z);
            acc.w = fmaf(h[j], w.w, acc.w);
        }
        float4 xn;
        xn.x = fmaf((xvv.x - mu1) * rs1, gv.x, bv.x);
        xn.y = fmaf((xvv.y - mu1) * rs1, gv.y, bv.y);
        xn.z = fmaf((xvv.z - mu1) * rs1, gv.z, bv.z);
        xn.w = fmaf((xvv.w - mu1) * rs1, gv.w, bv.w);
        acc.x = fmaf(xn.x, dk.x, acc.x);
        acc.y = fmaf(xn.y, dk.y, acc.y);
        acc.z = fmaf(xn.z, dk.z, acc.z);
        acc.w = fmaf(xn.w, dk.w, acc.w);
        float4 x2;
        x2.x = xvv.x + acc.x; x2.y = xvv.y + acc.y;
        x2.z = xvv.z + acc.z; x2.w = xvv.w + acc.w;
        st4(&Y[r * 2048 + i], x2);
        sum += x2.x + x2.y + x2.z + x2.w;
        ssq = fmaf(x2.x, x2.x, ssq); ssq = fmaf(x2.y, x2.y, ssq);
        ssq = fmaf(x2.z, x2.z, ssq); ssq = fmaf(x2.w, x2.w, ssq);
    }
#pragma unroll
    for (int off = 1; off < 32; off <<= 1) {
        sum += __shfl_xor(sum, off, 64);
        ssq += __shfl_xor(ssq, off, 64);
    }
    if (l == 0) {
        const float mu2 = sum * (1.f / D_MODEL);
        const float var = ssq * (1.f / D_MODEL) - mu2 * mu2;
        smu2[r] = mu2;
        srs2[r] = rsqrtf(var + EPSF);
    }
    __syncthreads();

    // Phase B
    const int wvb = t >> 6, lane = t & 63;
    const int jb = wvb * 8;
    float p[64];
#pragma unroll
    for (int v = 0; v < 64; ++v) p[v] = 0.f;
#pragma unroll 1
    for (int q = 0; q < 8; ++q) {
        const int ip = q * 256 + lane * 4;
        float4 yv[8];
#pragma unroll
        for (int rr = 0; rr < 8; ++rr) yv[rr] = ld4(&Y[rr * 2048 + ip]);
#pragma unroll
        for (int jj = 0; jj < 8; ++jj) {
            float4 w = ld4(ws + WS_WDT + (size_t)(jb + jj) * 2048 + ip);
#pragma unroll
            for (int rr = 0; rr < 8; ++rr) {
                p[rr*8+jj] = fmaf(yv[rr].x, w.x, p[rr*8+jj]);
                p[rr*8+jj] = fmaf(yv[rr].y, w.y, p[rr*8+jj]);
                p[rr*8+jj] = fmaf(yv[rr].z, w.z, p[rr*8+jj]);
                p[rr*8+jj] = fmaf(yv[rr].w, w.w, p[rr*8+jj]);
            }
        }
    }
    // split-butterfly reduce: lane ends with total for v = bitrev6(lane)
    {
        int count = 64;
#pragma unroll
        for (int step = 1; step <= 32; step <<= 1) {
            const int half = count >> 1;
            const bool up = (lane & step) != 0;
#pragma unroll
            for (int k = 0; k < 32; ++k) {
                if (k < half) {
                    float send = p[up ? k : k + half];
                    float keep = p[up ? k + half : k];
                    p[k] = keep + __shfl_xor(send, step, 64);
                }
            }
            count = half;
        }
    }
    {
        const int v = bitrev6(lane);
        const int r_ = v >> 3, j_ = v & 7;
        const float mu2r = smu2[r_], rs2r = srs2[r_];
        const float cj = ws[WS_C + jb + j_], dj = ws[WS_D + jb + j_];
        shf[r_ * 32 + jb + j_] =
            fmaxf(0.f, fmaf(rs2r, fmaf(-mu2r, cj, p[0]), dj));
    }
    __syncthreads();

    // Phase C: thread owns cols c0=t*4 and c0+1024 for all 8 rows
    const int c0 = t * 4;
    float4 a0[8], a1[8];
    const float4 bu0 = ld4(bu + c0), bu1 = ld4(bu + 1024 + c0);
#pragma unroll
    for (int rr = 0; rr < 8; ++rr) {
        float4 y0 = ld4(&Y[rr * 2048 + c0]);
        float4 y1 = ld4(&Y[rr * 2048 + 1024 + c0]);
        a0[rr] = make_float4(y0.x + bu0.x, y0.y + bu0.y, y0.z + bu0.z, y0.w + bu0.w);
        a1[rr] = make_float4(y1.x + bu1.x, y1.y + bu1.y, y1.z + bu1.z, y1.w + bu1.w);
    }
#pragma unroll 1
    for (int jc = 0; jc < 8; ++jc) {
        float hv[8][4];
#pragma unroll
        for (int rr = 0; rr < 8; ++rr) {
            float4 hq = ld4(&shf[rr * 32 + jc * 4]);
            hv[rr][0] = hq.x; hv[rr][1] = hq.y; hv[rr][2] = hq.z; hv[rr][3] = hq.w;
        }
#pragma unroll
        for (int jj = 0; jj < 4; ++jj) {
            const int j = jc * 4 + jj;
            const float4 w0 = ld4(Wu + (size_t)j * D_MODEL + c0);
            const float4 w1 = ld4(Wu + (size_t)j * D_MODEL + 1024 + c0);
#pragma unroll
            for (int rr = 0; rr < 8; ++rr) {
                const float hval = hv[rr][jj];
                a0[rr].x = fmaf(hval, w0.x, a0[rr].x);
                a0[rr].y = fmaf(hval, w0.y, a0[rr].y);
                a0[rr].z = fmaf(hval, w0.z, a0[rr].z);
                a0[rr].w = fmaf(hval, w0.w, a0[rr].w);
                a1[rr].x = fmaf(hval, w1.x, a1[rr].x);
                a1[rr].y = fmaf(hval, w1.y, a1[rr].y);
                a1[rr].z = fmaf(hval, w1.z, a1[rr].z);
                a1[rr].w = fmaf(hval, w1.w, a1[rr].w);
            }
        }
    }
#pragma unroll
    for (int rr = 0; rr < 8; ++rr) {
        float* orow = out + (size_t)(blk * 8 + rr) * D_MODEL;
        st4(orow + c0, a0[rr]);
        st4(orow + 1024 + c0, a1[rr]);
    }
}

// ---------------------------------------------------------------------------
extern "C" void kernel_launch(void* const* d_in, const int* in_sizes, int n_in,
                              void* d_out, int out_size, void* d_ws, size_t ws_size,
                              hipStream_t stream) {
    const float* x      = (const float*)d_in[0];
    const float* gamma  = (const float*)d_in[1];
    const float* beta   = (const float*)d_in[2];
    const float* Win    = (const float*)d_in[3];
    const float* b_in   = (const float*)d_in[4];
    const float* logit  = (const float*)d_in[5];
    const float* Wout   = (const float*)d_in[6];
    const float* b_out  = (const float*)d_in[7];
    const float* Dsk    = (const float*)d_in[8];
    const float* Wd     = (const float*)d_in[9];
    const float* bd     = (const float*)d_in[10];
    const float* Wu     = (const float*)d_in[11];
    const float* bu     = (const float*)d_in[12];
    float* out = (float*)d_out;
    float* ws  = (float*)d_ws;

    hipLaunchKernelGGL(k0_prep, dim3(10),   dim3(64),  0, stream,
                       Win, b_in, Wd, gamma, beta, bd, ws);
    hipLaunchKernelGGL(k1_ln_u, dim3(2048), dim3(256), 0, stream, x, ws);
    hipLaunchKernelGGL(k2_scan, dim3(32),   dim3(64),  0, stream, logit, ws);
    hipLaunchKernelGGL(k3_fused, dim3(2048), dim3(256), 0, stream,
                       x, gamma, beta, Wout, b_out, Dsk, Wu, bu, out, ws);
}